// Round 8
// baseline (229.767 us; speedup 1.0000x reference)
//
#include <hip/hip_runtime.h>

#define BN_EPS 1e-5f

typedef __attribute__((ext_vector_type(8))) short short8;
typedef __attribute__((ext_vector_type(8))) unsigned short ushort8v;
typedef __attribute__((ext_vector_type(4))) float floatx4;

#define GLL(gp, lp)                                                            \
    __builtin_amdgcn_global_load_lds(                                          \
        (const __attribute__((address_space(1))) void*)(gp),                   \
        (__attribute__((address_space(3))) void*)(lp), 16, 0, 0)

__device__ inline unsigned short f2bf(float f) {
    unsigned int u = __float_as_uint(f);
    unsigned int r = (u + 0x7FFF + ((u >> 16) & 1)) >> 16;  // RNE
    return (unsigned short)r;
}

__device__ inline float bf2f(unsigned short u) {
    return __uint_as_float(((unsigned int)u) << 16);
}

// ---------------- prep: count in-degree + fp32->bf16 casts (merged) --------

__global__ void prep_kernel(const int* __restrict__ col, int* __restrict__ cnt,
                            const float* __restrict__ x, const float* __restrict__ W1,
                            const float* __restrict__ W2, ushort* __restrict__ xbf,
                            ushort* __restrict__ W1bf, ushort* __restrict__ W2bf,
                            int E, int n4x, int n4w) {
    int i = blockIdx.x * blockDim.x + threadIdx.x;
    if (i < E) {
        atomicAdd(&cnt[col[i]], 1);
        return;
    }
    int j = i - E;
    const float* src;
    ushort* dst;
    if (j < n4x) { src = x; dst = xbf; }
    else if (j < n4x + n4w) { src = W1; dst = W1bf; j -= n4x; }
    else if (j < n4x + 2 * n4w) { src = W2; dst = W2bf; j -= n4x + n4w; }
    else return;
    float4 v = ((const float4*)src)[j];
    ushort4 o;
    o.x = f2bf(v.x); o.y = f2bf(v.y); o.z = f2bf(v.z); o.w = f2bf(v.w);
    ((ushort4*)dst)[j] = o;
}

// single-block scan over N counts -> rowptr/cursor; also computes dis.
__global__ __launch_bounds__(1024) void scan_dis_kernel(
    const int* __restrict__ cnt, float* __restrict__ dis,
    int* __restrict__ rowptr, int* __restrict__ cursor, int N) {
    __shared__ int sums[1024];
    int t = threadIdx.x;
    int per = (N + 1023) / 1024;
    int start = t * per;
    int local = 0;
    for (int i = 0; i < per; i++) {
        int idx = start + i;
        if (idx < N) {
            int cv = cnt[idx];
            local += cv;
            dis[idx] = rsqrtf((float)(cv + 1));   // +1 self loop
        }
    }
    sums[t] = local;
    __syncthreads();
    for (int off = 1; off < 1024; off <<= 1) {
        int v = (t >= off) ? sums[t - off] : 0;
        __syncthreads();
        sums[t] += v;
        __syncthreads();
    }
    int run = (t == 0) ? 0 : sums[t - 1];
    for (int i = 0; i < per; i++) {
        int idx = start + i;
        if (idx < N) {
            rowptr[idx] = run;
            cursor[idx] = run;
            run += cnt[idx];
        }
    }
    if (t == 0) rowptr[N] = sums[1023];
}

// scatter: build CSR adjacency with pre-baked dis[row].
__global__ void scatter_kernel(const int* __restrict__ row, const int* __restrict__ col,
                               const float* __restrict__ dis,
                               int* __restrict__ cursor, int2* __restrict__ adjw, int E) {
    int e = blockIdx.x * blockDim.x + threadIdx.x;
    if (e < E) {
        int r = row[e];
        int pos = atomicAdd(&cursor[col[e]], 1);
        adjw[pos] = make_int2(r, __float_as_int(dis[r]));
    }
}

// ---------------- bf16 gather, C=256 channels, one WAVE per node -----------
// Body = R3/R7-proven 2-deep unroll with 8 NAMED scalars (rule #20) + R7's
// coalesced adjacency preload + shfl broadcast. Wave-per-node removes LDS,
// barriers, and the idle-wave epilogue (R4's failure was a 16-accumulator
// helper spill, not wave-per-node itself). No barriers -> early return safe.

__global__ __launch_bounds__(256) void gather_bf_kernel(
    const ushort* __restrict__ xl, const int* __restrict__ rowptr,
    const int2* __restrict__ adjw, const float* __restrict__ dis,
    ushort* __restrict__ h, int Nn) {
    int wave = threadIdx.x >> 6;
    int lane = threadIdx.x & 63;
    int v = blockIdx.x * 4 + wave;
    if (v >= Nn) return;
    float dv = dis[v];

    int e0 = rowptr[v], e1 = rowptr[v + 1];
    int cnt = e1 - e0;
    // coalesced adjacency preload into lane registers (512B per wave)
    int pidx = e0 + lane;
    if (pidx >= e1) pidx = (e1 > 0) ? (e1 - 1) : 0;
    int2 am = adjw[pidx];
    int aidx = am.x;
    float awgt = __int_as_float(am.y) * dv;   // premultiplied weight

    int cnt64 = cnt < 64 ? cnt : 64;
    float a0 = 0.f, a1 = 0.f, a2 = 0.f, a3 = 0.f;
    float b0 = 0.f, b1 = 0.f, b2 = 0.f, b3 = 0.f;
    int j = 0;
    for (; j + 1 < cnt64; j += 2) {
        int ra = __shfl(aidx, j, 64);
        float wa = __shfl(awgt, j, 64);
        int rb = __shfl(aidx, j + 1, 64);
        float wb = __shfl(awgt, j + 1, 64);
        ushort4 ua = ((const ushort4*)xl)[(size_t)ra * 64 + lane];
        ushort4 ub = ((const ushort4*)xl)[(size_t)rb * 64 + lane];
        a0 = fmaf(bf2f(ua.x), wa, a0);
        a1 = fmaf(bf2f(ua.y), wa, a1);
        a2 = fmaf(bf2f(ua.z), wa, a2);
        a3 = fmaf(bf2f(ua.w), wa, a3);
        b0 = fmaf(bf2f(ub.x), wb, b0);
        b1 = fmaf(bf2f(ub.y), wb, b1);
        b2 = fmaf(bf2f(ub.z), wb, b2);
        b3 = fmaf(bf2f(ub.w), wb, b3);
    }
    if (j < cnt64) {
        int ra = __shfl(aidx, j, 64);
        float wa = __shfl(awgt, j, 64);
        ushort4 ua = ((const ushort4*)xl)[(size_t)ra * 64 + lane];
        a0 = fmaf(bf2f(ua.x), wa, a0);
        a1 = fmaf(bf2f(ua.y), wa, a1);
        a2 = fmaf(bf2f(ua.z), wa, a2);
        a3 = fmaf(bf2f(ua.w), wa, a3);
    }
    // rare tail: degree > 64 (negligible at mean degree 16)
    for (int e = e0 + 64; e < e1; e++) {
        int2 ea = adjw[e];
        float wa = __int_as_float(ea.y) * dv;
        ushort4 ua = ((const ushort4*)xl)[(size_t)ea.x * 64 + lane];
        a0 = fmaf(bf2f(ua.x), wa, a0);
        a1 = fmaf(bf2f(ua.y), wa, a1);
        a2 = fmaf(bf2f(ua.z), wa, a2);
        a3 = fmaf(bf2f(ua.w), wa, a3);
    }
    a0 += b0; a1 += b1; a2 += b2; a3 += b3;

    // self loop + store (every wave finishes its own node)
    ushort4 uv = ((const ushort4*)xl)[(size_t)v * 64 + lane];
    float w2 = dv * dv;
    a0 = fmaf(bf2f(uv.x), w2, a0);
    a1 = fmaf(bf2f(uv.y), w2, a1);
    a2 = fmaf(bf2f(uv.z), w2, a2);
    a3 = fmaf(bf2f(uv.w), w2, a3);
    ushort4 o;
    o.x = f2bf(a0); o.y = f2bf(a1); o.z = f2bf(a2); o.w = f2bf(a3);
    ((ushort4*)h)[(size_t)v * 64 + lane] = o;
}

// ---------------- MFMA GEMM: C[M,N] = A[M,K] @ B[N,K]^T (bf16 in/out) ------
// STATS: epilogue emits per-column partial sum/sumsq CHUNK-MAJOR into
//        psum[chunk*N + col] (coalesced write, enables coalesced prologue
//        reduce downstream).
// BN_A:  psum/psumsq are INPUTS (BN1 partials, chunk-major [chunks][K]);
//        bnScale/bnShift carry gamma1/beta1. Prologue reduces them COALESCED
//        (thread-per-channel, consecutive threads -> consecutive addresses;
//        no fence needed — dispatch boundary orders psum1 visibility) into
//        LDS scale/shift, then A-staging applies BN+ReLU in registers.
//        (Replaces the bn_reduce1 dispatch. R4's version of this was slow
//        because its reduce strided c*chunks+k — uncoalesced.)

template <bool STATS, bool BN_A>
__global__ __launch_bounds__(256) void gemm_mfma_kernel(
    const ushort* __restrict__ A, const ushort* __restrict__ B,
    ushort* __restrict__ Cout, float* __restrict__ psum, float* __restrict__ psumsq,
    const float* __restrict__ bnScale, const float* __restrict__ bnShift,
    int chunks, int M, int N, int K) {
    __shared__ ushort As[128 * 32];
    __shared__ ushort Bs[128 * 32];
    int tid = threadIdx.x;
    int wave = tid >> 6;
    int lane = tid & 63;
    int quad = lane >> 4;
    int l15 = lane & 15;
    int m0 = blockIdx.y * 128;
    int n0 = blockIdx.x * 128;

    int srow = lane >> 2;
    int skoff = (lane & 3) * 8;

    __shared__ float scL[512];
    __shared__ float shL[512];
    if (BN_A) {
        float invM = 1.0f / (float)M;
        for (int c = tid; c < K; c += 256) {
            float s = 0.f, q = 0.f;
            for (int k = 0; k < chunks; k++) {
                s += psum[(size_t)k * K + c];      // chunk-major: coalesced
                q += psumsq[(size_t)k * K + c];
            }
            float mean = s * invM;
            float var = q * invM - mean * mean;
            float sc = bnScale[c] * rsqrtf(var + BN_EPS);
            scL[c] = sc;
            shL[c] = bnShift[c] - mean * sc;
        }
        __syncthreads();
    }

    floatx4 acc[4][4];
#pragma unroll
    for (int i = 0; i < 4; i++)
#pragma unroll
        for (int j = 0; j < 4; j++) acc[i][j] = (floatx4){0.f, 0.f, 0.f, 0.f};

    int wm = (wave & 1) * 64;
    int wn = (wave >> 1) * 64;

    for (int k0 = 0; k0 < K; k0 += 32) {
#pragma unroll
        for (int cc = 0; cc < 2; cc++) {
            int c = wave * 2 + cc;
            int brow = n0 + c * 16 + srow;
            const ushort* gb = B + (size_t)brow * K + k0 + skoff;
            GLL(gb, (char*)Bs + c * 1024);
            if (!BN_A) {
                int arow = min(m0 + c * 16 + srow, M - 1);
                const ushort* ga = A + (size_t)arow * K + k0 + skoff;
                GLL(ga, (char*)As + c * 1024);
            }
        }
        if (BN_A) {
            float scv[8], shv[8];
#pragma unroll
            for (int j = 0; j < 8; j++) {
                scv[j] = scL[k0 + skoff + j];
                shv[j] = shL[k0 + skoff + j];
            }
#pragma unroll
            for (int cc = 0; cc < 2; cc++) {
                int c = wave * 2 + cc;
                int arow = min(m0 + c * 16 + srow, M - 1);
                ushort8v araw = *(const ushort8v*)(A + (size_t)arow * K + k0 + skoff);
                ushort8v t;
#pragma unroll
                for (int j = 0; j < 8; j++) {
                    float f = fmaxf(fmaf(bf2f(araw[j]), scv[j], shv[j]), 0.f);
                    t[j] = f2bf(f);
                }
                // tail barrier of previous iter guarantees buffer is free
                *(ushort8v*)((char*)As + c * 1024 + (size_t)lane * 16) = t;
            }
        }
        __syncthreads();

        short8 af[4], bfr[4];
#pragma unroll
        for (int i = 0; i < 4; i++) {
            int r = wm + i * 16 + l15;
            af[i] = *(const short8*)(As + r * 32 + quad * 8);
        }
#pragma unroll
        for (int j = 0; j < 4; j++) {
            int r = wn + j * 16 + l15;
            bfr[j] = *(const short8*)(Bs + r * 32 + quad * 8);
        }
#pragma unroll
        for (int i = 0; i < 4; i++)
#pragma unroll
            for (int j = 0; j < 4; j++)
                acc[i][j] = __builtin_amdgcn_mfma_f32_16x16x32_bf16(af[i], bfr[j], acc[i][j], 0, 0, 0);
        __syncthreads();
    }

#pragma unroll
    for (int i = 0; i < 4; i++) {
#pragma unroll
        for (int r = 0; r < 4; r++) {
            int row = m0 + wm + i * 16 + quad * 4 + r;
            if (row < M) {
                ushort* cp = Cout + (size_t)row * N + n0 + wn + l15;
#pragma unroll
                for (int j = 0; j < 4; j++) cp[j * 16] = f2bf(acc[i][j][r]);
            }
        }
    }

    if (STATS) {
        float s[4] = {0.f, 0.f, 0.f, 0.f};
        float q[4] = {0.f, 0.f, 0.f, 0.f};
#pragma unroll
        for (int i = 0; i < 4; i++) {
#pragma unroll
            for (int r = 0; r < 4; r++) {
                if (m0 + wm + i * 16 + quad * 4 + r < M) {
#pragma unroll
                    for (int j = 0; j < 4; j++) {
                        float v = acc[i][j][r];
                        s[j] += v;
                        q[j] += v * v;
                    }
                }
            }
        }
#pragma unroll
        for (int j = 0; j < 4; j++) {
            s[j] += __shfl_xor(s[j], 16, 64);
            s[j] += __shfl_xor(s[j], 32, 64);
            q[j] += __shfl_xor(q[j], 16, 64);
            q[j] += __shfl_xor(q[j], 32, 64);
        }
        __shared__ float sArr[4][64];
        __shared__ float qArr[4][64];
        if (quad == 0) {
#pragma unroll
            for (int j = 0; j < 4; j++) {
                sArr[wave][j * 16 + l15] = s[j];
                qArr[wave][j * 16 + l15] = q[j];
            }
        }
        __syncthreads();
        if (tid < 128) {
            int half = tid >> 6;
            int cc = tid & 63;
            float ss = sArr[half * 2][cc] + sArr[half * 2 + 1][cc];
            float qq = qArr[half * 2][cc] + qArr[half * 2 + 1][cc];
            int colI = n0 + half * 64 + cc;
            // chunk-major: [chunk][col] — coalesced across cc
            psum[(size_t)blockIdx.y * N + colI] = ss;
            psumsq[(size_t)blockIdx.y * N + colI] = qq;
        }
    }
}

// ---------------- BN2 partial stats on bf16 h (channel-major [C][chunks]) ---
// Non-atomic: each block owns its chunk column. Proven (~4us). Cross-block
// finalize stays a SEPARATE dispatch — fusion attempts cost 100-270us
// (atomics R1/R2, coop R4/R5, ticket+threadfence R6 incl. inside gemm1).

__global__ __launch_bounds__(256) void bn_partial_kernel(
    const ushort* __restrict__ h, float* __restrict__ psum, float* __restrict__ psumsq,
    int N, int IC, int rows_per_chunk, int chunks) {
    int groups = IC >> 2;          // 64 for C=256
    int rpi = 256 / groups;        // 4
    int t = threadIdx.x;
    int g = t & (groups - 1);
    int ro = t / groups;
    int r0 = blockIdx.x * rows_per_chunk;
    int r1 = min(r0 + rows_per_chunk, N);

    float4 s = make_float4(0.f, 0.f, 0.f, 0.f);
    float4 q = make_float4(0.f, 0.f, 0.f, 0.f);
    for (int r = r0 + ro; r < r1; r += rpi) {
        ushort4 u = *(const ushort4*)(h + (size_t)r * IC + g * 4);
        float vx = bf2f(u.x), vy = bf2f(u.y), vz = bf2f(u.z), vw = bf2f(u.w);
        s.x += vx; s.y += vy; s.z += vz; s.w += vw;
        q.x += vx * vx; q.y += vy * vy; q.z += vz * vz; q.w += vw * vw;
    }

    __shared__ float4 redS[256];
    __shared__ float4 redQ[256];
    redS[t] = s;
    redQ[t] = q;
    __syncthreads();
    if (ro == 0) {
        for (int i = 1; i < rpi; i++) {
            float4 o = redS[t + i * groups];
            s.x += o.x; s.y += o.y; s.z += o.z; s.w += o.w;
            float4 p = redQ[t + i * groups];
            q.x += p.x; q.y += p.y; q.z += p.z; q.w += p.w;
        }
        int k = blockIdx.x;
        psum[(size_t)(4 * g + 0) * chunks + k] = s.x;
        psum[(size_t)(4 * g + 1) * chunks + k] = s.y;
        psum[(size_t)(4 * g + 2) * chunks + k] = s.z;
        psum[(size_t)(4 * g + 3) * chunks + k] = s.w;
        psumsq[(size_t)(4 * g + 0) * chunks + k] = q.x;
        psumsq[(size_t)(4 * g + 1) * chunks + k] = q.y;
        psumsq[(size_t)(4 * g + 2) * chunks + k] = q.z;
        psumsq[(size_t)(4 * g + 3) * chunks + k] = q.w;
    }
}

// one wave per channel; coalesced lane-parallel reduce -> scale/shift.
__global__ __launch_bounds__(256) void bn_reduce_kernel(
    const float* __restrict__ psum, const float* __restrict__ psumsq,
    const float* __restrict__ gamma, const float* __restrict__ beta,
    float* __restrict__ scale, float* __restrict__ shift,
    int N, int chunks) {
    int wave = threadIdx.x >> 6;
    int lane = threadIdx.x & 63;
    int c = blockIdx.x * 4 + wave;
    float s = 0.f, q = 0.f;
    for (int k = lane; k < chunks; k += 64) {
        s += psum[(size_t)c * chunks + k];
        q += psumsq[(size_t)c * chunks + k];
    }
#pragma unroll
    for (int off = 32; off > 0; off >>= 1) {
        s += __shfl_down(s, off, 64);
        q += __shfl_down(q, off, 64);
    }
    if (lane == 0) {
        float invN = 1.0f / (float)N;
        float mean = s * invN;
        float var = q * invN - mean * mean;
        float sc = gamma[c] * rsqrtf(var + BN_EPS);
        scale[c] = sc;
        shift[c] = beta[c] - mean * sc;
    }
}

// ---------------- final: out = relu(bn2(h2) + x), large grid (bf16 h2) ------

__global__ void final_kernel(const ushort* __restrict__ h2, const float* __restrict__ x,
                             const float* __restrict__ scale, const float* __restrict__ shift,
                             float* __restrict__ out, int total4, int C4) {
    int idx = blockIdx.x * blockDim.x + threadIdx.x;
    if (idx >= total4) return;
    int c4 = (idx & (C4 - 1)) * 4;
    ushort4 u = ((const ushort4*)h2)[idx];
    float4 xv = ((const float4*)x)[idx];
    float4 o;
    o.x = fmaxf(fmaf(bf2f(u.x), scale[c4 + 0], shift[c4 + 0]) + xv.x, 0.f);
    o.y = fmaxf(fmaf(bf2f(u.y), scale[c4 + 1], shift[c4 + 1]) + xv.y, 0.f);
    o.z = fmaxf(fmaf(bf2f(u.z), scale[c4 + 2], shift[c4 + 2]) + xv.z, 0.f);
    o.w = fmaxf(fmaf(bf2f(u.w), scale[c4 + 3], shift[c4 + 3]) + xv.w, 0.f);
    ((float4*)out)[idx] = o;
}

// ---------------- launch ----------------

extern "C" void kernel_launch(void* const* d_in, const int* in_sizes, int n_in,
                              void* d_out, int out_size, void* d_ws, size_t ws_size,
                              hipStream_t stream) {
    const float* x  = (const float*)d_in[0];
    const int*   es = (const int*)d_in[1];
    const float* W1 = (const float*)d_in[2];
    const float* g1 = (const float*)d_in[3];
    const float* b1 = (const float*)d_in[4];
    const float* W2 = (const float*)d_in[5];
    const float* g2 = (const float*)d_in[6];
    const float* b2 = (const float*)d_in[7];
    float* out = (float*)d_out;

    const int E  = in_sizes[1] / 2;
    const int IC = in_sizes[3];   // 512
    const int C  = in_sizes[7];   // 256
    const int N  = in_sizes[0] / C;
    const int MTILES = (N + 127) / 128;   // 79
    const int CHUNKS2 = 512;

    const int* row = es;
    const int* col = es + E;

    // ---- workspace layout (cnt first: single memset) ----
    char* w = (char*)d_ws;
    size_t off = 0;
    auto alloc = [&](size_t bytes) -> void* {
        void* p = w + off;
        off = (off + bytes + 255) & ~(size_t)255;
        return p;
    };
    int*   cnt     = (int*)alloc((size_t)N * 4);
    float* dis     = (float*)alloc((size_t)N * 4);
    int*   rowptr  = (int*)alloc((size_t)(N + 1) * 4);
    int*   cursor  = (int*)alloc((size_t)N * 4);
    int2*  adjw    = (int2*)alloc((size_t)E * 8);
    float* psum1   = (float*)alloc((size_t)IC * MTILES * 4);
    float* psumsq1 = (float*)alloc((size_t)IC * MTILES * 4);
    float* psum2   = (float*)alloc((size_t)C * CHUNKS2 * 4);
    float* psumsq2 = (float*)alloc((size_t)C * CHUNKS2 * 4);
    float* scale2  = (float*)alloc((size_t)C * 4);
    float* shift2  = (float*)alloc((size_t)C * 4);
    ushort* xbf    = (ushort*)alloc((size_t)N * C * 2);
    ushort* W1bf   = (ushort*)alloc((size_t)IC * C * 2);
    ushort* W2bf   = (ushort*)alloc((size_t)IC * C * 2);
    ushort* g1x    = (ushort*)alloc((size_t)N * C * 2);
    ushort* h1raw  = (ushort*)alloc((size_t)N * IC * 2);  // GEMM1 out, bf16 (pre-BN)
    ushort* xl2bf  = (ushort*)alloc((size_t)N * C * 2);
    ushort* h2     = (ushort*)alloc((size_t)N * C * 2);   // gather2 out, bf16

    hipMemsetAsync(cnt, 0, (size_t)N * 4, stream);

    // ---- prep: degree count + bf16 casts ----
    {
        int n4x = N * C / 4, n4w = IC * C / 4;
        int tot = E + n4x + 2 * n4w;
        prep_kernel<<<(tot + 255) / 256, 256, 0, stream>>>(
            col, cnt, x, W1, W2, xbf, W1bf, W2bf, E, n4x, n4w);
    }
    scan_dis_kernel<<<1, 1024, 0, stream>>>(cnt, dis, rowptr, cursor, N);
    scatter_kernel<<<(E + 255) / 256, 256, 0, stream>>>(row, col, dis, cursor, adjw, E);

    // ---- layer 1: g1x = A_norm(x); h1raw = g1x @ W1^T (bf16 + stats1,
    //      chunk-major partials) ----
    gather_bf_kernel<<<(N + 3) / 4, 256, 0, stream>>>(xbf, rowptr, adjw, dis, g1x, N);
    {
        dim3 grid(IC / 128, MTILES);
        gemm_mfma_kernel<true, false><<<grid, 256, 0, stream>>>(
            g1x, W1bf, h1raw, psum1, psumsq1, nullptr, nullptr, MTILES, N, IC, C);
    }

    // ---- layer 2: GEMM2 prologue reduces BN1 partials (coalesced, replaces
    //      bn_reduce1); xl2 = relu(bn1(h1raw)) @ W2^T; h2 = A_norm(xl2) ----
    {
        dim3 grid(C / 128, MTILES);
        gemm_mfma_kernel<false, true><<<grid, 256, 0, stream>>>(
            h1raw, W2bf, xl2bf, psum1, psumsq1, g1, b1, MTILES, N, C, IC);
    }
    gather_bf_kernel<<<(N + 3) / 4, 256, 0, stream>>>(xl2bf, rowptr, adjw, dis, h2, N);
    {
        int rpc = (N + CHUNKS2 - 1) / CHUNKS2;
        bn_partial_kernel<<<CHUNKS2, 256, 0, stream>>>(h2, psum2, psumsq2, N, C, rpc, CHUNKS2);
    }
    bn_reduce_kernel<<<C / 4, 256, 0, stream>>>(psum2, psumsq2, g2, b2, scale2, shift2, N, CHUNKS2);

    // ---- epilogue: relu(bn2(h2) + x), saturating grid ----
    {
        int total4 = (N * C) / 4;
        final_kernel<<<(total4 + 255) / 256, 256, 0, stream>>>(h2, x, scale2, shift2, out, total4, C / 4);
    }
}

// Round 9
// 193.133 us; speedup vs baseline: 1.1897x; 1.1897x over previous
//
#include <hip/hip_runtime.h>

#define BN_EPS 1e-5f

typedef __attribute__((ext_vector_type(8))) short short8;
typedef __attribute__((ext_vector_type(8))) unsigned short ushort8v;
typedef __attribute__((ext_vector_type(4))) float floatx4;

#define GLL(gp, lp)                                                            \
    __builtin_amdgcn_global_load_lds(                                          \
        (const __attribute__((address_space(1))) void*)(gp),                   \
        (__attribute__((address_space(3))) void*)(lp), 16, 0, 0)

__device__ inline unsigned short f2bf(float f) {
    unsigned int u = __float_as_uint(f);
    unsigned int r = (u + 0x7FFF + ((u >> 16) & 1)) >> 16;  // RNE
    return (unsigned short)r;
}

__device__ inline float bf2f(unsigned short u) {
    return __uint_as_float(((unsigned int)u) << 16);
}

// ---------------- prep: count in-degree + fp32->bf16 casts (merged) --------

__global__ void prep_kernel(const int* __restrict__ col, int* __restrict__ cnt,
                            const float* __restrict__ x, const float* __restrict__ W1,
                            const float* __restrict__ W2, ushort* __restrict__ xbf,
                            ushort* __restrict__ W1bf, ushort* __restrict__ W2bf,
                            int E, int n4x, int n4w) {
    int i = blockIdx.x * blockDim.x + threadIdx.x;
    if (i < E) {
        atomicAdd(&cnt[col[i]], 1);
        return;
    }
    int j = i - E;
    const float* src;
    ushort* dst;
    if (j < n4x) { src = x; dst = xbf; }
    else if (j < n4x + n4w) { src = W1; dst = W1bf; j -= n4x; }
    else if (j < n4x + 2 * n4w) { src = W2; dst = W2bf; j -= n4x + n4w; }
    else return;
    float4 v = ((const float4*)src)[j];
    ushort4 o;
    o.x = f2bf(v.x); o.y = f2bf(v.y); o.z = f2bf(v.z); o.w = f2bf(v.w);
    ((ushort4*)dst)[j] = o;
}

// single-block scan over N counts -> rowptr/cursor; also computes dis.
__global__ __launch_bounds__(1024) void scan_dis_kernel(
    const int* __restrict__ cnt, float* __restrict__ dis,
    int* __restrict__ rowptr, int* __restrict__ cursor, int N) {
    __shared__ int sums[1024];
    int t = threadIdx.x;
    int per = (N + 1023) / 1024;
    int start = t * per;
    int local = 0;
    for (int i = 0; i < per; i++) {
        int idx = start + i;
        if (idx < N) {
            int cv = cnt[idx];
            local += cv;
            dis[idx] = rsqrtf((float)(cv + 1));   // +1 self loop
        }
    }
    sums[t] = local;
    __syncthreads();
    for (int off = 1; off < 1024; off <<= 1) {
        int v = (t >= off) ? sums[t - off] : 0;
        __syncthreads();
        sums[t] += v;
        __syncthreads();
    }
    int run = (t == 0) ? 0 : sums[t - 1];
    for (int i = 0; i < per; i++) {
        int idx = start + i;
        if (idx < N) {
            rowptr[idx] = run;
            cursor[idx] = run;
            run += cnt[idx];
        }
    }
    if (t == 0) rowptr[N] = sums[1023];
}

// scatter: build CSR adjacency with pre-baked dis[row].
__global__ void scatter_kernel(const int* __restrict__ row, const int* __restrict__ col,
                               const float* __restrict__ dis,
                               int* __restrict__ cursor, int2* __restrict__ adjw, int E) {
    int e = blockIdx.x * blockDim.x + threadIdx.x;
    if (e < E) {
        int r = row[e];
        int pos = atomicAdd(&cursor[col[e]], 1);
        adjw[pos] = make_int2(r, __float_as_int(dis[r]));
    }
}

// ---------------- bf16 gather, C=256 channels, one WAVE per node -----------
// ISOLATED EXPERIMENT vs R7 (195.0us): wave-per-node with the PROVEN
// 2-deep/8-named-scalar body + R7 shfl-preload. Removes 2 barriers, LDS
// round-trip, and the 3/4-idle-wave epilogue. R8 accounting says ~neutral;
// this round isolates it. Everything else in the file is R7-exact.

__global__ __launch_bounds__(256) void gather_bf_kernel(
    const ushort* __restrict__ xl, const int* __restrict__ rowptr,
    const int2* __restrict__ adjw, const float* __restrict__ dis,
    ushort* __restrict__ h, int Nn) {
    int wave = threadIdx.x >> 6;
    int lane = threadIdx.x & 63;
    int v = blockIdx.x * 4 + wave;
    if (v >= Nn) return;
    float dv = dis[v];

    int e0 = rowptr[v], e1 = rowptr[v + 1];
    int cnt = e1 - e0;
    // coalesced adjacency preload into lane registers (512B per wave)
    int pidx = e0 + lane;
    if (pidx >= e1) pidx = (e1 > 0) ? (e1 - 1) : 0;
    int2 am = adjw[pidx];
    int aidx = am.x;
    float awgt = __int_as_float(am.y) * dv;   // premultiplied weight

    int cnt64 = cnt < 64 ? cnt : 64;
    float a0 = 0.f, a1 = 0.f, a2 = 0.f, a3 = 0.f;
    float b0 = 0.f, b1 = 0.f, b2 = 0.f, b3 = 0.f;
    int j = 0;
    for (; j + 1 < cnt64; j += 2) {
        int ra = __shfl(aidx, j, 64);
        float wa = __shfl(awgt, j, 64);
        int rb = __shfl(aidx, j + 1, 64);
        float wb = __shfl(awgt, j + 1, 64);
        ushort4 ua = ((const ushort4*)xl)[(size_t)ra * 64 + lane];
        ushort4 ub = ((const ushort4*)xl)[(size_t)rb * 64 + lane];
        a0 = fmaf(bf2f(ua.x), wa, a0);
        a1 = fmaf(bf2f(ua.y), wa, a1);
        a2 = fmaf(bf2f(ua.z), wa, a2);
        a3 = fmaf(bf2f(ua.w), wa, a3);
        b0 = fmaf(bf2f(ub.x), wb, b0);
        b1 = fmaf(bf2f(ub.y), wb, b1);
        b2 = fmaf(bf2f(ub.z), wb, b2);
        b3 = fmaf(bf2f(ub.w), wb, b3);
    }
    if (j < cnt64) {
        int ra = __shfl(aidx, j, 64);
        float wa = __shfl(awgt, j, 64);
        ushort4 ua = ((const ushort4*)xl)[(size_t)ra * 64 + lane];
        a0 = fmaf(bf2f(ua.x), wa, a0);
        a1 = fmaf(bf2f(ua.y), wa, a1);
        a2 = fmaf(bf2f(ua.z), wa, a2);
        a3 = fmaf(bf2f(ua.w), wa, a3);
    }
    // rare tail: degree > 64 (negligible at mean degree 16)
    for (int e = e0 + 64; e < e1; e++) {
        int2 ea = adjw[e];
        float wa = __int_as_float(ea.y) * dv;
        ushort4 ua = ((const ushort4*)xl)[(size_t)ea.x * 64 + lane];
        a0 = fmaf(bf2f(ua.x), wa, a0);
        a1 = fmaf(bf2f(ua.y), wa, a1);
        a2 = fmaf(bf2f(ua.z), wa, a2);
        a3 = fmaf(bf2f(ua.w), wa, a3);
    }
    a0 += b0; a1 += b1; a2 += b2; a3 += b3;

    // self loop + store (every wave finishes its own node)
    ushort4 uv = ((const ushort4*)xl)[(size_t)v * 64 + lane];
    float w2 = dv * dv;
    a0 = fmaf(bf2f(uv.x), w2, a0);
    a1 = fmaf(bf2f(uv.y), w2, a1);
    a2 = fmaf(bf2f(uv.z), w2, a2);
    a3 = fmaf(bf2f(uv.w), w2, a3);
    ushort4 o;
    o.x = f2bf(a0); o.y = f2bf(a1); o.z = f2bf(a2); o.w = f2bf(a3);
    ((ushort4*)h)[(size_t)v * 64 + lane] = o;
}

// ---------------- MFMA GEMM: C[M,N] = A[M,K] @ B[N,K]^T (bf16 in/out) ------
// R7-EXACT. STATS: channel-major psum[col][chunk] partials (separate
// bn_reduce dispatch finalizes — 4 fusion mechanisms all lost: atomics
// R1/R2, coop R4/R5, ticket+fence R6, per-block re-reduce R8).
// BN_A: A-staging applies BN(scale,shift from global)+ReLU in registers.

template <bool STATS, bool BN_A>
__global__ __launch_bounds__(256) void gemm_mfma_kernel(
    const ushort* __restrict__ A, const ushort* __restrict__ B,
    ushort* __restrict__ Cout, float* __restrict__ psum, float* __restrict__ psumsq,
    const float* __restrict__ bnScale, const float* __restrict__ bnShift,
    int chunks, int M, int N, int K) {
    __shared__ ushort As[128 * 32];
    __shared__ ushort Bs[128 * 32];
    int tid = threadIdx.x;
    int wave = tid >> 6;
    int lane = tid & 63;
    int quad = lane >> 4;
    int l15 = lane & 15;
    int m0 = blockIdx.y * 128;
    int n0 = blockIdx.x * 128;

    int srow = lane >> 2;
    int skoff = (lane & 3) * 8;

    floatx4 acc[4][4];
#pragma unroll
    for (int i = 0; i < 4; i++)
#pragma unroll
        for (int j = 0; j < 4; j++) acc[i][j] = (floatx4){0.f, 0.f, 0.f, 0.f};

    int wm = (wave & 1) * 64;
    int wn = (wave >> 1) * 64;

    for (int k0 = 0; k0 < K; k0 += 32) {
#pragma unroll
        for (int cc = 0; cc < 2; cc++) {
            int c = wave * 2 + cc;
            int brow = n0 + c * 16 + srow;
            const ushort* gb = B + (size_t)brow * K + k0 + skoff;
            GLL(gb, (char*)Bs + c * 1024);
            if (!BN_A) {
                int arow = min(m0 + c * 16 + srow, M - 1);
                const ushort* ga = A + (size_t)arow * K + k0 + skoff;
                GLL(ga, (char*)As + c * 1024);
            }
        }
        if (BN_A) {
            const float* scp = bnScale + k0 + skoff;
            const float* shp = bnShift + k0 + skoff;
            float4 sa = *(const float4*)scp;
            float4 sb = *(const float4*)(scp + 4);
            float4 ha = *(const float4*)shp;
            float4 hb = *(const float4*)(shp + 4);
            float scv[8] = {sa.x, sa.y, sa.z, sa.w, sb.x, sb.y, sb.z, sb.w};
            float shv[8] = {ha.x, ha.y, ha.z, ha.w, hb.x, hb.y, hb.z, hb.w};
#pragma unroll
            for (int cc = 0; cc < 2; cc++) {
                int c = wave * 2 + cc;
                int arow = min(m0 + c * 16 + srow, M - 1);
                ushort8v araw = *(const ushort8v*)(A + (size_t)arow * K + k0 + skoff);
                ushort8v t;
#pragma unroll
                for (int j = 0; j < 8; j++) {
                    float f = fmaxf(fmaf(bf2f(araw[j]), scv[j], shv[j]), 0.f);
                    t[j] = f2bf(f);
                }
                // tail barrier of previous iter guarantees buffer is free
                *(ushort8v*)((char*)As + c * 1024 + (size_t)lane * 16) = t;
            }
        }
        __syncthreads();

        short8 af[4], bfr[4];
#pragma unroll
        for (int i = 0; i < 4; i++) {
            int r = wm + i * 16 + l15;
            af[i] = *(const short8*)(As + r * 32 + quad * 8);
        }
#pragma unroll
        for (int j = 0; j < 4; j++) {
            int r = wn + j * 16 + l15;
            bfr[j] = *(const short8*)(Bs + r * 32 + quad * 8);
        }
#pragma unroll
        for (int i = 0; i < 4; i++)
#pragma unroll
            for (int j = 0; j < 4; j++)
                acc[i][j] = __builtin_amdgcn_mfma_f32_16x16x32_bf16(af[i], bfr[j], acc[i][j], 0, 0, 0);
        __syncthreads();
    }

#pragma unroll
    for (int i = 0; i < 4; i++) {
#pragma unroll
        for (int r = 0; r < 4; r++) {
            int row = m0 + wm + i * 16 + quad * 4 + r;
            if (row < M) {
                ushort* cp = Cout + (size_t)row * N + n0 + wn + l15;
#pragma unroll
                for (int j = 0; j < 4; j++) cp[j * 16] = f2bf(acc[i][j][r]);
            }
        }
    }

    if (STATS) {
        float s[4] = {0.f, 0.f, 0.f, 0.f};
        float q[4] = {0.f, 0.f, 0.f, 0.f};
#pragma unroll
        for (int i = 0; i < 4; i++) {
#pragma unroll
            for (int r = 0; r < 4; r++) {
                if (m0 + wm + i * 16 + quad * 4 + r < M) {
#pragma unroll
                    for (int j = 0; j < 4; j++) {
                        float v = acc[i][j][r];
                        s[j] += v;
                        q[j] += v * v;
                    }
                }
            }
        }
#pragma unroll
        for (int j = 0; j < 4; j++) {
            s[j] += __shfl_xor(s[j], 16, 64);
            s[j] += __shfl_xor(s[j], 32, 64);
            q[j] += __shfl_xor(q[j], 16, 64);
            q[j] += __shfl_xor(q[j], 32, 64);
        }
        __shared__ float sArr[4][64];
        __shared__ float qArr[4][64];
        if (quad == 0) {
#pragma unroll
            for (int j = 0; j < 4; j++) {
                sArr[wave][j * 16 + l15] = s[j];
                qArr[wave][j * 16 + l15] = q[j];
            }
        }
        __syncthreads();
        if (tid < 128) {
            int half = tid >> 6;
            int cc = tid & 63;
            float ss = sArr[half * 2][cc] + sArr[half * 2 + 1][cc];
            float qq = qArr[half * 2][cc] + qArr[half * 2 + 1][cc];
            int colI = n0 + half * 64 + cc;
            psum[(size_t)colI * chunks + blockIdx.y] = ss;
            psumsq[(size_t)colI * chunks + blockIdx.y] = qq;
        }
    }
}

// ---------------- BN2 partial stats on bf16 h (channel-major [C][chunks]) ---

__global__ __launch_bounds__(256) void bn_partial_kernel(
    const ushort* __restrict__ h, float* __restrict__ psum, float* __restrict__ psumsq,
    int N, int IC, int rows_per_chunk, int chunks) {
    int groups = IC >> 2;          // 64 for C=256
    int rpi = 256 / groups;        // 4
    int t = threadIdx.x;
    int g = t & (groups - 1);
    int ro = t / groups;
    int r0 = blockIdx.x * rows_per_chunk;
    int r1 = min(r0 + rows_per_chunk, N);

    float4 s = make_float4(0.f, 0.f, 0.f, 0.f);
    float4 q = make_float4(0.f, 0.f, 0.f, 0.f);
    for (int r = r0 + ro; r < r1; r += rpi) {
        ushort4 u = *(const ushort4*)(h + (size_t)r * IC + g * 4);
        float vx = bf2f(u.x), vy = bf2f(u.y), vz = bf2f(u.z), vw = bf2f(u.w);
        s.x += vx; s.y += vy; s.z += vz; s.w += vw;
        q.x += vx * vx; q.y += vy * vy; q.z += vz * vz; q.w += vw * vw;
    }

    __shared__ float4 redS[256];
    __shared__ float4 redQ[256];
    redS[t] = s;
    redQ[t] = q;
    __syncthreads();
    if (ro == 0) {
        for (int i = 1; i < rpi; i++) {
            float4 o = redS[t + i * groups];
            s.x += o.x; s.y += o.y; s.z += o.z; s.w += o.w;
            float4 p = redQ[t + i * groups];
            q.x += p.x; q.y += p.y; q.z += p.z; q.w += p.w;
        }
        int k = blockIdx.x;
        psum[(size_t)(4 * g + 0) * chunks + k] = s.x;
        psum[(size_t)(4 * g + 1) * chunks + k] = s.y;
        psum[(size_t)(4 * g + 2) * chunks + k] = s.z;
        psum[(size_t)(4 * g + 3) * chunks + k] = s.w;
        psumsq[(size_t)(4 * g + 0) * chunks + k] = q.x;
        psumsq[(size_t)(4 * g + 1) * chunks + k] = q.y;
        psumsq[(size_t)(4 * g + 2) * chunks + k] = q.z;
        psumsq[(size_t)(4 * g + 3) * chunks + k] = q.w;
    }
}

// one wave per channel; coalesced lane-parallel reduce -> scale/shift.
__global__ __launch_bounds__(256) void bn_reduce_kernel(
    const float* __restrict__ psum, const float* __restrict__ psumsq,
    const float* __restrict__ gamma, const float* __restrict__ beta,
    float* __restrict__ scale, float* __restrict__ shift,
    int N, int chunks) {
    int wave = threadIdx.x >> 6;
    int lane = threadIdx.x & 63;
    int c = blockIdx.x * 4 + wave;
    float s = 0.f, q = 0.f;
    for (int k = lane; k < chunks; k += 64) {
        s += psum[(size_t)c * chunks + k];
        q += psumsq[(size_t)c * chunks + k];
    }
#pragma unroll
    for (int off = 32; off > 0; off >>= 1) {
        s += __shfl_down(s, off, 64);
        q += __shfl_down(q, off, 64);
    }
    if (lane == 0) {
        float invN = 1.0f / (float)N;
        float mean = s * invN;
        float var = q * invN - mean * mean;
        float sc = gamma[c] * rsqrtf(var + BN_EPS);
        scale[c] = sc;
        shift[c] = beta[c] - mean * sc;
    }
}

// ---------------- final: out = relu(bn2(h2) + x), large grid (bf16 h2) ------

__global__ void final_kernel(const ushort* __restrict__ h2, const float* __restrict__ x,
                             const float* __restrict__ scale, const float* __restrict__ shift,
                             float* __restrict__ out, int total4, int C4) {
    int idx = blockIdx.x * blockDim.x + threadIdx.x;
    if (idx >= total4) return;
    int c4 = (idx & (C4 - 1)) * 4;
    ushort4 u = ((const ushort4*)h2)[idx];
    float4 xv = ((const float4*)x)[idx];
    float4 o;
    o.x = fmaxf(fmaf(bf2f(u.x), scale[c4 + 0], shift[c4 + 0]) + xv.x, 0.f);
    o.y = fmaxf(fmaf(bf2f(u.y), scale[c4 + 1], shift[c4 + 1]) + xv.y, 0.f);
    o.z = fmaxf(fmaf(bf2f(u.z), scale[c4 + 2], shift[c4 + 2]) + xv.z, 0.f);
    o.w = fmaxf(fmaf(bf2f(u.w), scale[c4 + 3], shift[c4 + 3]) + xv.w, 0.f);
    ((float4*)out)[idx] = o;
}

// ---------------- launch ----------------

extern "C" void kernel_launch(void* const* d_in, const int* in_sizes, int n_in,
                              void* d_out, int out_size, void* d_ws, size_t ws_size,
                              hipStream_t stream) {
    const float* x  = (const float*)d_in[0];
    const int*   es = (const int*)d_in[1];
    const float* W1 = (const float*)d_in[2];
    const float* g1 = (const float*)d_in[3];
    const float* b1 = (const float*)d_in[4];
    const float* W2 = (const float*)d_in[5];
    const float* g2 = (const float*)d_in[6];
    const float* b2 = (const float*)d_in[7];
    float* out = (float*)d_out;

    const int E  = in_sizes[1] / 2;
    const int IC = in_sizes[3];   // 512
    const int C  = in_sizes[7];   // 256
    const int N  = in_sizes[0] / C;
    const int MTILES = (N + 127) / 128;   // 79
    const int CHUNKS2 = 512;

    const int* row = es;
    const int* col = es + E;

    // ---- workspace layout (cnt first: single memset) ----
    char* w = (char*)d_ws;
    size_t off = 0;
    auto alloc = [&](size_t bytes) -> void* {
        void* p = w + off;
        off = (off + bytes + 255) & ~(size_t)255;
        return p;
    };
    int*   cnt     = (int*)alloc((size_t)N * 4);
    float* dis     = (float*)alloc((size_t)N * 4);
    int*   rowptr  = (int*)alloc((size_t)(N + 1) * 4);
    int*   cursor  = (int*)alloc((size_t)N * 4);
    int2*  adjw    = (int2*)alloc((size_t)E * 8);
    float* psum1   = (float*)alloc((size_t)IC * MTILES * 4);
    float* psumsq1 = (float*)alloc((size_t)IC * MTILES * 4);
    float* psum2   = (float*)alloc((size_t)C * CHUNKS2 * 4);
    float* psumsq2 = (float*)alloc((size_t)C * CHUNKS2 * 4);
    float* scale1  = (float*)alloc((size_t)IC * 4);
    float* shift1  = (float*)alloc((size_t)IC * 4);
    float* scale2  = (float*)alloc((size_t)C * 4);
    float* shift2  = (float*)alloc((size_t)C * 4);
    ushort* xbf    = (ushort*)alloc((size_t)N * C * 2);
    ushort* W1bf   = (ushort*)alloc((size_t)IC * C * 2);
    ushort* W2bf   = (ushort*)alloc((size_t)IC * C * 2);
    ushort* g1x    = (ushort*)alloc((size_t)N * C * 2);
    ushort* h1raw  = (ushort*)alloc((size_t)N * IC * 2);  // GEMM1 out, bf16 (pre-BN)
    ushort* xl2bf  = (ushort*)alloc((size_t)N * C * 2);
    ushort* h2     = (ushort*)alloc((size_t)N * C * 2);   // gather2 out, bf16

    hipMemsetAsync(cnt, 0, (size_t)N * 4, stream);

    // ---- prep: degree count + bf16 casts ----
    {
        int n4x = N * C / 4, n4w = IC * C / 4;
        int tot = E + n4x + 2 * n4w;
        prep_kernel<<<(tot + 255) / 256, 256, 0, stream>>>(
            col, cnt, x, W1, W2, xbf, W1bf, W2bf, E, n4x, n4w);
    }
    scan_dis_kernel<<<1, 1024, 0, stream>>>(cnt, dis, rowptr, cursor, N);
    scatter_kernel<<<(E + 255) / 256, 256, 0, stream>>>(row, col, dis, cursor, adjw, E);

    // ---- layer 1: g1x = A_norm(x); h1raw = g1x @ W1^T (bf16 + stats1) ----
    gather_bf_kernel<<<(N + 3) / 4, 256, 0, stream>>>(xbf, rowptr, adjw, dis, g1x, N);
    {
        dim3 grid(IC / 128, MTILES);
        gemm_mfma_kernel<true, false><<<grid, 256, 0, stream>>>(
            g1x, W1bf, h1raw, psum1, psumsq1, nullptr, nullptr, MTILES, N, IC, C);
    }
    bn_reduce_kernel<<<IC / 4, 256, 0, stream>>>(psum1, psumsq1, g1, b1, scale1, shift1, N, MTILES);

    // ---- layer 2: xl2 = relu(bn1(h1raw)) @ W2^T (BN fused into A staging);
    //      h2 = A_norm(xl2) ----
    {
        dim3 grid(C / 128, MTILES);
        gemm_mfma_kernel<false, true><<<grid, 256, 0, stream>>>(
            h1raw, W2bf, xl2bf, scale1, shift1, scale1, shift1, 0, N, C, IC);
    }
    gather_bf_kernel<<<(N + 3) / 4, 256, 0, stream>>>(xl2bf, rowptr, adjw, dis, h2, N);
    {
        int rpc = (N + CHUNKS2 - 1) / CHUNKS2;
        bn_partial_kernel<<<CHUNKS2, 256, 0, stream>>>(h2, psum2, psumsq2, N, C, rpc, CHUNKS2);
    }
    bn_reduce_kernel<<<C / 4, 256, 0, stream>>>(psum2, psumsq2, g2, b2, scale2, shift2, N, CHUNKS2);

    // ---- epilogue: relu(bn2(h2) + x), saturating grid ----
    {
        int total4 = (N * C) / 4;
        final_kernel<<<(total4 + 255) / 256, 256, 0, stream>>>(h2, x, scale2, shift2, out, total4, C / 4);
    }
}

// Round 10
// 189.080 us; speedup vs baseline: 1.2152x; 1.0214x over previous
//
#include <hip/hip_runtime.h>

#define BN_EPS 1e-5f

typedef __attribute__((ext_vector_type(8))) short short8;
typedef __attribute__((ext_vector_type(8))) unsigned short ushort8v;
typedef __attribute__((ext_vector_type(4))) float floatx4;

#define GLL(gp, lp)                                                            \
    __builtin_amdgcn_global_load_lds(                                          \
        (const __attribute__((address_space(1))) void*)(gp),                   \
        (__attribute__((address_space(3))) void*)(lp), 16, 0, 0)

__device__ inline unsigned short f2bf(float f) {
    unsigned int u = __float_as_uint(f);
    unsigned int r = (u + 0x7FFF + ((u >> 16) & 1)) >> 16;  // RNE
    return (unsigned short)r;
}

__device__ inline float bf2f(unsigned short u) {
    return __uint_as_float(((unsigned int)u) << 16);
}

// ---------------- prep: count in-degree + fp32->bf16 casts (merged) --------

__global__ void prep_kernel(const int* __restrict__ col, int* __restrict__ cnt,
                            const float* __restrict__ x, const float* __restrict__ W1,
                            const float* __restrict__ W2, ushort* __restrict__ xbf,
                            ushort* __restrict__ W1bf, ushort* __restrict__ W2bf,
                            int E, int n4x, int n4w) {
    int i = blockIdx.x * blockDim.x + threadIdx.x;
    if (i < E) {
        atomicAdd(&cnt[col[i]], 1);
        return;
    }
    int j = i - E;
    const float* src;
    ushort* dst;
    if (j < n4x) { src = x; dst = xbf; }
    else if (j < n4x + n4w) { src = W1; dst = W1bf; j -= n4x; }
    else if (j < n4x + 2 * n4w) { src = W2; dst = W2bf; j -= n4x + n4w; }
    else return;
    float4 v = ((const float4*)src)[j];
    ushort4 o;
    o.x = f2bf(v.x); o.y = f2bf(v.y); o.z = f2bf(v.z); o.w = f2bf(v.w);
    ((ushort4*)dst)[j] = o;
}

// single-block scan over N counts -> rowptr/cursor; also computes dis.
__global__ __launch_bounds__(1024) void scan_dis_kernel(
    const int* __restrict__ cnt, float* __restrict__ dis,
    int* __restrict__ rowptr, int* __restrict__ cursor, int N) {
    __shared__ int sums[1024];
    int t = threadIdx.x;
    int per = (N + 1023) / 1024;
    int start = t * per;
    int local = 0;
    for (int i = 0; i < per; i++) {
        int idx = start + i;
        if (idx < N) {
            int cv = cnt[idx];
            local += cv;
            dis[idx] = rsqrtf((float)(cv + 1));   // +1 self loop
        }
    }
    sums[t] = local;
    __syncthreads();
    for (int off = 1; off < 1024; off <<= 1) {
        int v = (t >= off) ? sums[t - off] : 0;
        __syncthreads();
        sums[t] += v;
        __syncthreads();
    }
    int run = (t == 0) ? 0 : sums[t - 1];
    for (int i = 0; i < per; i++) {
        int idx = start + i;
        if (idx < N) {
            rowptr[idx] = run;
            cursor[idx] = run;
            run += cnt[idx];
        }
    }
    if (t == 0) rowptr[N] = sums[1023];
}

// scatter: build CSR adjacency with pre-baked dis[row].
__global__ void scatter_kernel(const int* __restrict__ row, const int* __restrict__ col,
                               const float* __restrict__ dis,
                               int* __restrict__ cursor, int2* __restrict__ adjw, int E) {
    int e = blockIdx.x * blockDim.x + threadIdx.x;
    if (e < E) {
        int r = row[e];
        int pos = atomicAdd(&cursor[col[e]], 1);
        adjw[pos] = make_int2(r, __float_as_int(dis[r]));
    }
}

// ---------------- bf16 gather, C=256 channels, one WAVE per node -----------
// R9-PROVEN (193.1us): wave-per-node, 2-deep/8-named-scalar body, coalesced
// adjacency preload + shfl broadcast. Do not restructure.

__global__ __launch_bounds__(256) void gather_bf_kernel(
    const ushort* __restrict__ xl, const int* __restrict__ rowptr,
    const int2* __restrict__ adjw, const float* __restrict__ dis,
    ushort* __restrict__ h, int Nn) {
    int wave = threadIdx.x >> 6;
    int lane = threadIdx.x & 63;
    int v = blockIdx.x * 4 + wave;
    if (v >= Nn) return;
    float dv = dis[v];

    int e0 = rowptr[v], e1 = rowptr[v + 1];
    int cnt = e1 - e0;
    // coalesced adjacency preload into lane registers (512B per wave)
    int pidx = e0 + lane;
    if (pidx >= e1) pidx = (e1 > 0) ? (e1 - 1) : 0;
    int2 am = adjw[pidx];
    int aidx = am.x;
    float awgt = __int_as_float(am.y) * dv;   // premultiplied weight

    int cnt64 = cnt < 64 ? cnt : 64;
    float a0 = 0.f, a1 = 0.f, a2 = 0.f, a3 = 0.f;
    float b0 = 0.f, b1 = 0.f, b2 = 0.f, b3 = 0.f;
    int j = 0;
    for (; j + 1 < cnt64; j += 2) {
        int ra = __shfl(aidx, j, 64);
        float wa = __shfl(awgt, j, 64);
        int rb = __shfl(aidx, j + 1, 64);
        float wb = __shfl(awgt, j + 1, 64);
        ushort4 ua = ((const ushort4*)xl)[(size_t)ra * 64 + lane];
        ushort4 ub = ((const ushort4*)xl)[(size_t)rb * 64 + lane];
        a0 = fmaf(bf2f(ua.x), wa, a0);
        a1 = fmaf(bf2f(ua.y), wa, a1);
        a2 = fmaf(bf2f(ua.z), wa, a2);
        a3 = fmaf(bf2f(ua.w), wa, a3);
        b0 = fmaf(bf2f(ub.x), wb, b0);
        b1 = fmaf(bf2f(ub.y), wb, b1);
        b2 = fmaf(bf2f(ub.z), wb, b2);
        b3 = fmaf(bf2f(ub.w), wb, b3);
    }
    if (j < cnt64) {
        int ra = __shfl(aidx, j, 64);
        float wa = __shfl(awgt, j, 64);
        ushort4 ua = ((const ushort4*)xl)[(size_t)ra * 64 + lane];
        a0 = fmaf(bf2f(ua.x), wa, a0);
        a1 = fmaf(bf2f(ua.y), wa, a1);
        a2 = fmaf(bf2f(ua.z), wa, a2);
        a3 = fmaf(bf2f(ua.w), wa, a3);
    }
    // rare tail: degree > 64 (negligible at mean degree 16)
    for (int e = e0 + 64; e < e1; e++) {
        int2 ea = adjw[e];
        float wa = __int_as_float(ea.y) * dv;
        ushort4 ua = ((const ushort4*)xl)[(size_t)ea.x * 64 + lane];
        a0 = fmaf(bf2f(ua.x), wa, a0);
        a1 = fmaf(bf2f(ua.y), wa, a1);
        a2 = fmaf(bf2f(ua.z), wa, a2);
        a3 = fmaf(bf2f(ua.w), wa, a3);
    }
    a0 += b0; a1 += b1; a2 += b2; a3 += b3;

    // self loop + store (every wave finishes its own node)
    ushort4 uv = ((const ushort4*)xl)[(size_t)v * 64 + lane];
    float w2 = dv * dv;
    a0 = fmaf(bf2f(uv.x), w2, a0);
    a1 = fmaf(bf2f(uv.y), w2, a1);
    a2 = fmaf(bf2f(uv.z), w2, a2);
    a3 = fmaf(bf2f(uv.w), w2, a3);
    ushort4 o;
    o.x = f2bf(a0); o.y = f2bf(a1); o.z = f2bf(a2); o.w = f2bf(a3);
    ((ushort4*)h)[(size_t)v * 64 + lane] = o;
}

// ---------------- MFMA GEMM: C[M,N] = A[M,K] @ B[N,K]^T (bf16 in/out) ------
// BM=64 x BN=128 tile (was 128x128): doubles grid.y -> 628/314 blocks so all
// 256 CUs are busy with 2+ blocks (R8 counters: occupancy 6.6%, grid 158 <
// 256 CUs = the GEMM bottleneck). Wave layout 1x4: per-wave 64x32 output,
// acc[4][2]; all waves share rows, own distinct cols -> STATS epilogue needs
// no LDS combine. LDS 12KB. Fragment/staging lane math unchanged per chunk.
// STATS: psum[col][chunk] partials, separate bn_reduce finalize (4 fusion
// mechanisms lost: atomics R1/R2, coop R4/R5, ticket+fence R6, re-reduce R8).
// BN_A: A-staging applies BN(scale,shift)+ReLU in registers.

template <bool STATS, bool BN_A>
__global__ __launch_bounds__(256) void gemm_mfma_kernel(
    const ushort* __restrict__ A, const ushort* __restrict__ B,
    ushort* __restrict__ Cout, float* __restrict__ psum, float* __restrict__ psumsq,
    const float* __restrict__ bnScale, const float* __restrict__ bnShift,
    int chunks, int M, int N, int K) {
    __shared__ ushort As[64 * 32];
    __shared__ ushort Bs[128 * 32];
    int tid = threadIdx.x;
    int wave = tid >> 6;
    int lane = tid & 63;
    int quad = lane >> 4;
    int l15 = lane & 15;
    int m0 = blockIdx.y * 64;
    int n0 = blockIdx.x * 128;

    int srow = lane >> 2;
    int skoff = (lane & 3) * 8;

    floatx4 acc[4][2];
#pragma unroll
    for (int i = 0; i < 4; i++)
#pragma unroll
        for (int j = 0; j < 2; j++) acc[i][j] = (floatx4){0.f, 0.f, 0.f, 0.f};

    int wn = wave * 32;

    for (int k0 = 0; k0 < K; k0 += 32) {
        // B staging: 8 chunks of 16 rows, 2 per wave
#pragma unroll
        for (int cc = 0; cc < 2; cc++) {
            int c = wave * 2 + cc;
            int brow = n0 + c * 16 + srow;
            const ushort* gb = B + (size_t)brow * K + k0 + skoff;
            GLL(gb, (char*)Bs + c * 1024);
        }
        // A staging: 4 chunks of 16 rows, 1 per wave
        if (!BN_A) {
            int arow = min(m0 + wave * 16 + srow, M - 1);
            const ushort* ga = A + (size_t)arow * K + k0 + skoff;
            GLL(ga, (char*)As + wave * 1024);
        } else {
            const float* scp = bnScale + k0 + skoff;
            const float* shp = bnShift + k0 + skoff;
            float4 sa = *(const float4*)scp;
            float4 sb = *(const float4*)(scp + 4);
            float4 ha = *(const float4*)shp;
            float4 hb = *(const float4*)(shp + 4);
            float scv[8] = {sa.x, sa.y, sa.z, sa.w, sb.x, sb.y, sb.z, sb.w};
            float shv[8] = {ha.x, ha.y, ha.z, ha.w, hb.x, hb.y, hb.z, hb.w};
            int arow = min(m0 + wave * 16 + srow, M - 1);
            ushort8v araw = *(const ushort8v*)(A + (size_t)arow * K + k0 + skoff);
            ushort8v t;
#pragma unroll
            for (int j = 0; j < 8; j++) {
                float f = fmaxf(fmaf(bf2f(araw[j]), scv[j], shv[j]), 0.f);
                t[j] = f2bf(f);
            }
            // tail barrier of previous iter guarantees buffer is free
            *(ushort8v*)((char*)As + wave * 1024 + (size_t)lane * 16) = t;
        }
        __syncthreads();

        short8 af[4], bfr[2];
#pragma unroll
        for (int i = 0; i < 4; i++) {
            int r = i * 16 + l15;
            af[i] = *(const short8*)(As + r * 32 + quad * 8);
        }
#pragma unroll
        for (int j = 0; j < 2; j++) {
            int r = wn + j * 16 + l15;
            bfr[j] = *(const short8*)(Bs + r * 32 + quad * 8);
        }
#pragma unroll
        for (int i = 0; i < 4; i++)
#pragma unroll
            for (int j = 0; j < 2; j++)
                acc[i][j] = __builtin_amdgcn_mfma_f32_16x16x32_bf16(af[i], bfr[j], acc[i][j], 0, 0, 0);
        __syncthreads();
    }

#pragma unroll
    for (int i = 0; i < 4; i++) {
#pragma unroll
        for (int r = 0; r < 4; r++) {
            int row = m0 + i * 16 + quad * 4 + r;
            if (row < M) {
                ushort* cp = Cout + (size_t)row * N + n0 + wn + l15;
#pragma unroll
                for (int j = 0; j < 2; j++) cp[j * 16] = f2bf(acc[i][j][r]);
            }
        }
    }

    if (STATS) {
        float s[2] = {0.f, 0.f};
        float q[2] = {0.f, 0.f};
#pragma unroll
        for (int i = 0; i < 4; i++) {
#pragma unroll
            for (int r = 0; r < 4; r++) {
                if (m0 + i * 16 + quad * 4 + r < M) {
#pragma unroll
                    for (int j = 0; j < 2; j++) {
                        float v = acc[i][j][r];
                        s[j] += v;
                        q[j] += v * v;
                    }
                }
            }
        }
        // sum over the 4 quads (same column, different row blocks)
#pragma unroll
        for (int j = 0; j < 2; j++) {
            s[j] += __shfl_xor(s[j], 16, 64);
            s[j] += __shfl_xor(s[j], 32, 64);
            q[j] += __shfl_xor(q[j], 16, 64);
            q[j] += __shfl_xor(q[j], 32, 64);
        }
        if (quad == 0) {
            // each (wave, j, l15) owns a distinct column — no LDS combine
#pragma unroll
            for (int j = 0; j < 2; j++) {
                int colI = n0 + wn + j * 16 + l15;
                psum[(size_t)colI * chunks + blockIdx.y] = s[j];
                psumsq[(size_t)colI * chunks + blockIdx.y] = q[j];
            }
        }
    }
}

// ---------------- BN2 partial stats on bf16 h (channel-major [C][chunks]) ---

__global__ __launch_bounds__(256) void bn_partial_kernel(
    const ushort* __restrict__ h, float* __restrict__ psum, float* __restrict__ psumsq,
    int N, int IC, int rows_per_chunk, int chunks) {
    int groups = IC >> 2;          // 64 for C=256
    int rpi = 256 / groups;        // 4
    int t = threadIdx.x;
    int g = t & (groups - 1);
    int ro = t / groups;
    int r0 = blockIdx.x * rows_per_chunk;
    int r1 = min(r0 + rows_per_chunk, N);

    float4 s = make_float4(0.f, 0.f, 0.f, 0.f);
    float4 q = make_float4(0.f, 0.f, 0.f, 0.f);
    for (int r = r0 + ro; r < r1; r += rpi) {
        ushort4 u = *(const ushort4*)(h + (size_t)r * IC + g * 4);
        float vx = bf2f(u.x), vy = bf2f(u.y), vz = bf2f(u.z), vw = bf2f(u.w);
        s.x += vx; s.y += vy; s.z += vz; s.w += vw;
        q.x += vx * vx; q.y += vy * vy; q.z += vz * vz; q.w += vw * vw;
    }

    __shared__ float4 redS[256];
    __shared__ float4 redQ[256];
    redS[t] = s;
    redQ[t] = q;
    __syncthreads();
    if (ro == 0) {
        for (int i = 1; i < rpi; i++) {
            float4 o = redS[t + i * groups];
            s.x += o.x; s.y += o.y; s.z += o.z; s.w += o.w;
            float4 p = redQ[t + i * groups];
            q.x += p.x; q.y += p.y; q.z += p.z; q.w += p.w;
        }
        int k = blockIdx.x;
        psum[(size_t)(4 * g + 0) * chunks + k] = s.x;
        psum[(size_t)(4 * g + 1) * chunks + k] = s.y;
        psum[(size_t)(4 * g + 2) * chunks + k] = s.z;
        psum[(size_t)(4 * g + 3) * chunks + k] = s.w;
        psumsq[(size_t)(4 * g + 0) * chunks + k] = q.x;
        psumsq[(size_t)(4 * g + 1) * chunks + k] = q.y;
        psumsq[(size_t)(4 * g + 2) * chunks + k] = q.z;
        psumsq[(size_t)(4 * g + 3) * chunks + k] = q.w;
    }
}

// one wave per channel; coalesced lane-parallel reduce -> scale/shift.
__global__ __launch_bounds__(256) void bn_reduce_kernel(
    const float* __restrict__ psum, const float* __restrict__ psumsq,
    const float* __restrict__ gamma, const float* __restrict__ beta,
    float* __restrict__ scale, float* __restrict__ shift,
    int N, int chunks) {
    int wave = threadIdx.x >> 6;
    int lane = threadIdx.x & 63;
    int c = blockIdx.x * 4 + wave;
    float s = 0.f, q = 0.f;
    for (int k = lane; k < chunks; k += 64) {
        s += psum[(size_t)c * chunks + k];
        q += psumsq[(size_t)c * chunks + k];
    }
#pragma unroll
    for (int off = 32; off > 0; off >>= 1) {
        s += __shfl_down(s, off, 64);
        q += __shfl_down(q, off, 64);
    }
    if (lane == 0) {
        float invN = 1.0f / (float)N;
        float mean = s * invN;
        float var = q * invN - mean * mean;
        float sc = gamma[c] * rsqrtf(var + BN_EPS);
        scale[c] = sc;
        shift[c] = beta[c] - mean * sc;
    }
}

// ---------------- final: out = relu(bn2(h2) + x), large grid (bf16 h2) ------

__global__ void final_kernel(const ushort* __restrict__ h2, const float* __restrict__ x,
                             const float* __restrict__ scale, const float* __restrict__ shift,
                             float* __restrict__ out, int total4, int C4) {
    int idx = blockIdx.x * blockDim.x + threadIdx.x;
    if (idx >= total4) return;
    int c4 = (idx & (C4 - 1)) * 4;
    ushort4 u = ((const ushort4*)h2)[idx];
    float4 xv = ((const float4*)x)[idx];
    float4 o;
    o.x = fmaxf(fmaf(bf2f(u.x), scale[c4 + 0], shift[c4 + 0]) + xv.x, 0.f);
    o.y = fmaxf(fmaf(bf2f(u.y), scale[c4 + 1], shift[c4 + 1]) + xv.y, 0.f);
    o.z = fmaxf(fmaf(bf2f(u.z), scale[c4 + 2], shift[c4 + 2]) + xv.z, 0.f);
    o.w = fmaxf(fmaf(bf2f(u.w), scale[c4 + 3], shift[c4 + 3]) + xv.w, 0.f);
    ((float4*)out)[idx] = o;
}

// ---------------- launch ----------------

extern "C" void kernel_launch(void* const* d_in, const int* in_sizes, int n_in,
                              void* d_out, int out_size, void* d_ws, size_t ws_size,
                              hipStream_t stream) {
    const float* x  = (const float*)d_in[0];
    const int*   es = (const int*)d_in[1];
    const float* W1 = (const float*)d_in[2];
    const float* g1 = (const float*)d_in[3];
    const float* b1 = (const float*)d_in[4];
    const float* W2 = (const float*)d_in[5];
    const float* g2 = (const float*)d_in[6];
    const float* b2 = (const float*)d_in[7];
    float* out = (float*)d_out;

    const int E  = in_sizes[1] / 2;
    const int IC = in_sizes[3];   // 512
    const int C  = in_sizes[7];   // 256
    const int N  = in_sizes[0] / C;
    const int MTILES = (N + 63) / 64;     // 157 (BM=64)
    const int CHUNKS2 = 512;

    const int* row = es;
    const int* col = es + E;

    // ---- workspace layout (cnt first: single memset) ----
    char* w = (char*)d_ws;
    size_t off = 0;
    auto alloc = [&](size_t bytes) -> void* {
        void* p = w + off;
        off = (off + bytes + 255) & ~(size_t)255;
        return p;
    };
    int*   cnt     = (int*)alloc((size_t)N * 4);
    float* dis     = (float*)alloc((size_t)N * 4);
    int*   rowptr  = (int*)alloc((size_t)(N + 1) * 4);
    int*   cursor  = (int*)alloc((size_t)N * 4);
    int2*  adjw    = (int2*)alloc((size_t)E * 8);
    float* psum1   = (float*)alloc((size_t)IC * MTILES * 4);
    float* psumsq1 = (float*)alloc((size_t)IC * MTILES * 4);
    float* psum2   = (float*)alloc((size_t)C * CHUNKS2 * 4);
    float* psumsq2 = (float*)alloc((size_t)C * CHUNKS2 * 4);
    float* scale1  = (float*)alloc((size_t)IC * 4);
    float* shift1  = (float*)alloc((size_t)IC * 4);
    float* scale2  = (float*)alloc((size_t)C * 4);
    float* shift2  = (float*)alloc((size_t)C * 4);
    ushort* xbf    = (ushort*)alloc((size_t)N * C * 2);
    ushort* W1bf   = (ushort*)alloc((size_t)IC * C * 2);
    ushort* W2bf   = (ushort*)alloc((size_t)IC * C * 2);
    ushort* g1x    = (ushort*)alloc((size_t)N * C * 2);
    ushort* h1raw  = (ushort*)alloc((size_t)N * IC * 2);  // GEMM1 out, bf16 (pre-BN)
    ushort* xl2bf  = (ushort*)alloc((size_t)N * C * 2);
    ushort* h2     = (ushort*)alloc((size_t)N * C * 2);   // gather2 out, bf16

    hipMemsetAsync(cnt, 0, (size_t)N * 4, stream);

    // ---- prep: degree count + bf16 casts ----
    {
        int n4x = N * C / 4, n4w = IC * C / 4;
        int tot = E + n4x + 2 * n4w;
        prep_kernel<<<(tot + 255) / 256, 256, 0, stream>>>(
            col, cnt, x, W1, W2, xbf, W1bf, W2bf, E, n4x, n4w);
    }
    scan_dis_kernel<<<1, 1024, 0, stream>>>(cnt, dis, rowptr, cursor, N);
    scatter_kernel<<<(E + 255) / 256, 256, 0, stream>>>(row, col, dis, cursor, adjw, E);

    // ---- layer 1: g1x = A_norm(x); h1raw = g1x @ W1^T (bf16 + stats1) ----
    gather_bf_kernel<<<(N + 3) / 4, 256, 0, stream>>>(xbf, rowptr, adjw, dis, g1x, N);
    {
        dim3 grid(IC / 128, MTILES);
        gemm_mfma_kernel<true, false><<<grid, 256, 0, stream>>>(
            g1x, W1bf, h1raw, psum1, psumsq1, nullptr, nullptr, MTILES, N, IC, C);
    }
    bn_reduce_kernel<<<IC / 4, 256, 0, stream>>>(psum1, psumsq1, g1, b1, scale1, shift1, N, MTILES);

    // ---- layer 2: xl2 = relu(bn1(h1raw)) @ W2^T (BN fused into A staging);
    //      h2 = A_norm(xl2) ----
    {
        dim3 grid(C / 128, MTILES);
        gemm_mfma_kernel<false, true><<<grid, 256, 0, stream>>>(
            h1raw, W2bf, xl2bf, scale1, shift1, scale1, shift1, 0, N, C, IC);
    }
    gather_bf_kernel<<<(N + 3) / 4, 256, 0, stream>>>(xl2bf, rowptr, adjw, dis, h2, N);
    {
        int rpc = (N + CHUNKS2 - 1) / CHUNKS2;
        bn_partial_kernel<<<CHUNKS2, 256, 0, stream>>>(h2, psum2, psumsq2, N, C, rpc, CHUNKS2);
    }
    bn_reduce_kernel<<<C / 4, 256, 0, stream>>>(psum2, psumsq2, g2, b2, scale2, shift2, N, CHUNKS2);

    // ---- epilogue: relu(bn2(h2) + x), saturating grid ----
    {
        int total4 = (N * C) / 4;
        final_kernel<<<(total4 + 255) / 256, 256, 0, stream>>>(h2, x, scale2, shift2, out, total4, C / 4);
    }
}

// Round 11
// 185.354 us; speedup vs baseline: 1.2396x; 1.0201x over previous
//
#include <hip/hip_runtime.h>

#define BN_EPS 1e-5f

typedef __attribute__((ext_vector_type(8))) short short8;
typedef __attribute__((ext_vector_type(8))) unsigned short ushort8v;
typedef __attribute__((ext_vector_type(4))) float floatx4;

#define GLL(gp, lp)                                                            \
    __builtin_amdgcn_global_load_lds(                                          \
        (const __attribute__((address_space(1))) void*)(gp),                   \
        (__attribute__((address_space(3))) void*)(lp), 16, 0, 0)

__device__ inline unsigned short f2bf(float f) {
    unsigned int u = __float_as_uint(f);
    unsigned int r = (u + 0x7FFF + ((u >> 16) & 1)) >> 16;  // RNE
    return (unsigned short)r;
}

__device__ inline float bf2f(unsigned short u) {
    return __uint_as_float(((unsigned int)u) << 16);
}

// ---------------- prep: count in-degree + fp32->bf16 casts (merged) --------

__global__ void prep_kernel(const int* __restrict__ col, int* __restrict__ cnt,
                            const float* __restrict__ x, const float* __restrict__ W1,
                            const float* __restrict__ W2, ushort* __restrict__ xbf,
                            ushort* __restrict__ W1bf, ushort* __restrict__ W2bf,
                            int E, int n4x, int n4w) {
    int i = blockIdx.x * blockDim.x + threadIdx.x;
    if (i < E) {
        atomicAdd(&cnt[col[i]], 1);
        return;
    }
    int j = i - E;
    const float* src;
    ushort* dst;
    if (j < n4x) { src = x; dst = xbf; }
    else if (j < n4x + n4w) { src = W1; dst = W1bf; j -= n4x; }
    else if (j < n4x + 2 * n4w) { src = W2; dst = W2bf; j -= n4x + n4w; }
    else return;
    float4 v = ((const float4*)src)[j];
    ushort4 o;
    o.x = f2bf(v.x); o.y = f2bf(v.y); o.z = f2bf(v.z); o.w = f2bf(v.w);
    ((ushort4*)dst)[j] = o;
}

// single-block scan over N counts -> rowptr/cursor; also computes dis.
__global__ __launch_bounds__(1024) void scan_dis_kernel(
    const int* __restrict__ cnt, float* __restrict__ dis,
    int* __restrict__ rowptr, int* __restrict__ cursor, int N) {
    __shared__ int sums[1024];
    int t = threadIdx.x;
    int per = (N + 1023) / 1024;
    int start = t * per;
    int local = 0;
    for (int i = 0; i < per; i++) {
        int idx = start + i;
        if (idx < N) {
            int cv = cnt[idx];
            local += cv;
            dis[idx] = rsqrtf((float)(cv + 1));   // +1 self loop
        }
    }
    sums[t] = local;
    __syncthreads();
    for (int off = 1; off < 1024; off <<= 1) {
        int v = (t >= off) ? sums[t - off] : 0;
        __syncthreads();
        sums[t] += v;
        __syncthreads();
    }
    int run = (t == 0) ? 0 : sums[t - 1];
    for (int i = 0; i < per; i++) {
        int idx = start + i;
        if (idx < N) {
            rowptr[idx] = run;
            cursor[idx] = run;
            run += cnt[idx];
        }
    }
    if (t == 0) rowptr[N] = sums[1023];
}

// scatter: build CSR adjacency with pre-baked dis[row].
__global__ void scatter_kernel(const int* __restrict__ row, const int* __restrict__ col,
                               const float* __restrict__ dis,
                               int* __restrict__ cursor, int2* __restrict__ adjw, int E) {
    int e = blockIdx.x * blockDim.x + threadIdx.x;
    if (e < E) {
        int r = row[e];
        int pos = atomicAdd(&cursor[col[e]], 1);
        adjw[pos] = make_int2(r, __float_as_int(dis[r]));
    }
}

// ---------------- bf16 gather, C=256 channels, one WAVE per node -----------
// R9/R10-proven wave-per-node + shfl-preload. This round: 4-deep edge unroll
// (was 2-deep) to double MLP in the latency-bound edge loop. 16 NAMED scalar
// accumulators + 4 named ushort4 temps, in-body (rule #20; R4's collapse used
// an acc[] array inside a returning helper — structurally different).

__global__ __launch_bounds__(256) void gather_bf_kernel(
    const ushort* __restrict__ xl, const int* __restrict__ rowptr,
    const int2* __restrict__ adjw, const float* __restrict__ dis,
    ushort* __restrict__ h, int Nn) {
    int wave = threadIdx.x >> 6;
    int lane = threadIdx.x & 63;
    int v = blockIdx.x * 4 + wave;
    if (v >= Nn) return;
    float dv = dis[v];

    int e0 = rowptr[v], e1 = rowptr[v + 1];
    int cnt = e1 - e0;
    // coalesced adjacency preload into lane registers (512B per wave)
    int pidx = e0 + lane;
    if (pidx >= e1) pidx = (e1 > 0) ? (e1 - 1) : 0;
    int2 am = adjw[pidx];
    int aidx = am.x;
    float awgt = __int_as_float(am.y) * dv;   // premultiplied weight

    int cnt64 = cnt < 64 ? cnt : 64;
    float p0 = 0.f, p1 = 0.f, p2 = 0.f, p3 = 0.f;
    float q0 = 0.f, q1 = 0.f, q2 = 0.f, q3 = 0.f;
    float r0 = 0.f, r1 = 0.f, r2 = 0.f, r3 = 0.f;
    float s0 = 0.f, s1 = 0.f, s2 = 0.f, s3 = 0.f;
    int j = 0;
    for (; j + 3 < cnt64; j += 4) {
        int ia = __shfl(aidx, j, 64);
        float wa = __shfl(awgt, j, 64);
        int ib = __shfl(aidx, j + 1, 64);
        float wb = __shfl(awgt, j + 1, 64);
        int ic = __shfl(aidx, j + 2, 64);
        float wc = __shfl(awgt, j + 2, 64);
        int id = __shfl(aidx, j + 3, 64);
        float wd = __shfl(awgt, j + 3, 64);
        ushort4 ua = ((const ushort4*)xl)[(size_t)ia * 64 + lane];
        ushort4 ub = ((const ushort4*)xl)[(size_t)ib * 64 + lane];
        ushort4 uc = ((const ushort4*)xl)[(size_t)ic * 64 + lane];
        ushort4 ud = ((const ushort4*)xl)[(size_t)id * 64 + lane];
        p0 = fmaf(bf2f(ua.x), wa, p0);
        p1 = fmaf(bf2f(ua.y), wa, p1);
        p2 = fmaf(bf2f(ua.z), wa, p2);
        p3 = fmaf(bf2f(ua.w), wa, p3);
        q0 = fmaf(bf2f(ub.x), wb, q0);
        q1 = fmaf(bf2f(ub.y), wb, q1);
        q2 = fmaf(bf2f(ub.z), wb, q2);
        q3 = fmaf(bf2f(ub.w), wb, q3);
        r0 = fmaf(bf2f(uc.x), wc, r0);
        r1 = fmaf(bf2f(uc.y), wc, r1);
        r2 = fmaf(bf2f(uc.z), wc, r2);
        r3 = fmaf(bf2f(uc.w), wc, r3);
        s0 = fmaf(bf2f(ud.x), wd, s0);
        s1 = fmaf(bf2f(ud.y), wd, s1);
        s2 = fmaf(bf2f(ud.z), wd, s2);
        s3 = fmaf(bf2f(ud.w), wd, s3);
    }
    for (; j < cnt64; j++) {
        int ia = __shfl(aidx, j, 64);
        float wa = __shfl(awgt, j, 64);
        ushort4 ua = ((const ushort4*)xl)[(size_t)ia * 64 + lane];
        p0 = fmaf(bf2f(ua.x), wa, p0);
        p1 = fmaf(bf2f(ua.y), wa, p1);
        p2 = fmaf(bf2f(ua.z), wa, p2);
        p3 = fmaf(bf2f(ua.w), wa, p3);
    }
    // rare tail: degree > 64 (negligible at mean degree 16)
    for (int e = e0 + 64; e < e1; e++) {
        int2 ea = adjw[e];
        float wa = __int_as_float(ea.y) * dv;
        ushort4 ua = ((const ushort4*)xl)[(size_t)ea.x * 64 + lane];
        p0 = fmaf(bf2f(ua.x), wa, p0);
        p1 = fmaf(bf2f(ua.y), wa, p1);
        p2 = fmaf(bf2f(ua.z), wa, p2);
        p3 = fmaf(bf2f(ua.w), wa, p3);
    }
    p0 += q0 + r0 + s0;
    p1 += q1 + r1 + s1;
    p2 += q2 + r2 + s2;
    p3 += q3 + r3 + s3;

    // self loop + store (every wave finishes its own node)
    ushort4 uv = ((const ushort4*)xl)[(size_t)v * 64 + lane];
    float w2 = dv * dv;
    p0 = fmaf(bf2f(uv.x), w2, p0);
    p1 = fmaf(bf2f(uv.y), w2, p1);
    p2 = fmaf(bf2f(uv.z), w2, p2);
    p3 = fmaf(bf2f(uv.w), w2, p3);
    ushort4 o;
    o.x = f2bf(p0); o.y = f2bf(p1); o.z = f2bf(p2); o.w = f2bf(p3);
    ((ushort4*)h)[(size_t)v * 64 + lane] = o;
}

// ---------------- MFMA GEMM: C[M,N] = A[M,K] @ B[N,K]^T (bf16 in/out) ------
// R10-PROVEN: BM=64 x BN=128 tile, grid 628/314 blocks (all 256 CUs busy).
// Wave layout 1x4, acc[4][2], STATS epilogue without LDS combine.
// STATS: psum[col][chunk] partials, separate bn_reduce finalize (4 fusion
// mechanisms lost: atomics R1/R2, coop R4/R5, ticket+fence R6, re-reduce R8).
// BN_A: A-staging applies BN(scale,shift)+ReLU in registers.

template <bool STATS, bool BN_A>
__global__ __launch_bounds__(256) void gemm_mfma_kernel(
    const ushort* __restrict__ A, const ushort* __restrict__ B,
    ushort* __restrict__ Cout, float* __restrict__ psum, float* __restrict__ psumsq,
    const float* __restrict__ bnScale, const float* __restrict__ bnShift,
    int chunks, int M, int N, int K) {
    __shared__ ushort As[64 * 32];
    __shared__ ushort Bs[128 * 32];
    int tid = threadIdx.x;
    int wave = tid >> 6;
    int lane = tid & 63;
    int quad = lane >> 4;
    int l15 = lane & 15;
    int m0 = blockIdx.y * 64;
    int n0 = blockIdx.x * 128;

    int srow = lane >> 2;
    int skoff = (lane & 3) * 8;

    floatx4 acc[4][2];
#pragma unroll
    for (int i = 0; i < 4; i++)
#pragma unroll
        for (int j = 0; j < 2; j++) acc[i][j] = (floatx4){0.f, 0.f, 0.f, 0.f};

    int wn = wave * 32;

    for (int k0 = 0; k0 < K; k0 += 32) {
        // B staging: 8 chunks of 16 rows, 2 per wave
#pragma unroll
        for (int cc = 0; cc < 2; cc++) {
            int c = wave * 2 + cc;
            int brow = n0 + c * 16 + srow;
            const ushort* gb = B + (size_t)brow * K + k0 + skoff;
            GLL(gb, (char*)Bs + c * 1024);
        }
        // A staging: 4 chunks of 16 rows, 1 per wave
        if (!BN_A) {
            int arow = min(m0 + wave * 16 + srow, M - 1);
            const ushort* ga = A + (size_t)arow * K + k0 + skoff;
            GLL(ga, (char*)As + wave * 1024);
        } else {
            const float* scp = bnScale + k0 + skoff;
            const float* shp = bnShift + k0 + skoff;
            float4 sa = *(const float4*)scp;
            float4 sb = *(const float4*)(scp + 4);
            float4 ha = *(const float4*)shp;
            float4 hb = *(const float4*)(shp + 4);
            float scv[8] = {sa.x, sa.y, sa.z, sa.w, sb.x, sb.y, sb.z, sb.w};
            float shv[8] = {ha.x, ha.y, ha.z, ha.w, hb.x, hb.y, hb.z, hb.w};
            int arow = min(m0 + wave * 16 + srow, M - 1);
            ushort8v araw = *(const ushort8v*)(A + (size_t)arow * K + k0 + skoff);
            ushort8v t;
#pragma unroll
            for (int j = 0; j < 8; j++) {
                float f = fmaxf(fmaf(bf2f(araw[j]), scv[j], shv[j]), 0.f);
                t[j] = f2bf(f);
            }
            // tail barrier of previous iter guarantees buffer is free
            *(ushort8v*)((char*)As + wave * 1024 + (size_t)lane * 16) = t;
        }
        __syncthreads();

        short8 af[4], bfr[2];
#pragma unroll
        for (int i = 0; i < 4; i++) {
            int r = i * 16 + l15;
            af[i] = *(const short8*)(As + r * 32 + quad * 8);
        }
#pragma unroll
        for (int j = 0; j < 2; j++) {
            int r = wn + j * 16 + l15;
            bfr[j] = *(const short8*)(Bs + r * 32 + quad * 8);
        }
#pragma unroll
        for (int i = 0; i < 4; i++)
#pragma unroll
            for (int j = 0; j < 2; j++)
                acc[i][j] = __builtin_amdgcn_mfma_f32_16x16x32_bf16(af[i], bfr[j], acc[i][j], 0, 0, 0);
        __syncthreads();
    }

#pragma unroll
    for (int i = 0; i < 4; i++) {
#pragma unroll
        for (int r = 0; r < 4; r++) {
            int row = m0 + i * 16 + quad * 4 + r;
            if (row < M) {
                ushort* cp = Cout + (size_t)row * N + n0 + wn + l15;
#pragma unroll
                for (int j = 0; j < 2; j++) cp[j * 16] = f2bf(acc[i][j][r]);
            }
        }
    }

    if (STATS) {
        float s[2] = {0.f, 0.f};
        float q[2] = {0.f, 0.f};
#pragma unroll
        for (int i = 0; i < 4; i++) {
#pragma unroll
            for (int r = 0; r < 4; r++) {
                if (m0 + i * 16 + quad * 4 + r < M) {
#pragma unroll
                    for (int j = 0; j < 2; j++) {
                        float v = acc[i][j][r];
                        s[j] += v;
                        q[j] += v * v;
                    }
                }
            }
        }
        // sum over the 4 quads (same column, different row blocks)
#pragma unroll
        for (int j = 0; j < 2; j++) {
            s[j] += __shfl_xor(s[j], 16, 64);
            s[j] += __shfl_xor(s[j], 32, 64);
            q[j] += __shfl_xor(q[j], 16, 64);
            q[j] += __shfl_xor(q[j], 32, 64);
        }
        if (quad == 0) {
            // each (wave, j, l15) owns a distinct column — no LDS combine
#pragma unroll
            for (int j = 0; j < 2; j++) {
                int colI = n0 + wn + j * 16 + l15;
                psum[(size_t)colI * chunks + blockIdx.y] = s[j];
                psumsq[(size_t)colI * chunks + blockIdx.y] = q[j];
            }
        }
    }
}

// ---------------- BN2 partial stats on bf16 h (channel-major [C][chunks]) ---

__global__ __launch_bounds__(256) void bn_partial_kernel(
    const ushort* __restrict__ h, float* __restrict__ psum, float* __restrict__ psumsq,
    int N, int IC, int rows_per_chunk, int chunks) {
    int groups = IC >> 2;          // 64 for C=256
    int rpi = 256 / groups;        // 4
    int t = threadIdx.x;
    int g = t & (groups - 1);
    int ro = t / groups;
    int r0 = blockIdx.x * rows_per_chunk;
    int r1 = min(r0 + rows_per_chunk, N);

    float4 s = make_float4(0.f, 0.f, 0.f, 0.f);
    float4 q = make_float4(0.f, 0.f, 0.f, 0.f);
    for (int r = r0 + ro; r < r1; r += rpi) {
        ushort4 u = *(const ushort4*)(h + (size_t)r * IC + g * 4);
        float vx = bf2f(u.x), vy = bf2f(u.y), vz = bf2f(u.z), vw = bf2f(u.w);
        s.x += vx; s.y += vy; s.z += vz; s.w += vw;
        q.x += vx * vx; q.y += vy * vy; q.z += vz * vz; q.w += vw * vw;
    }

    __shared__ float4 redS[256];
    __shared__ float4 redQ[256];
    redS[t] = s;
    redQ[t] = q;
    __syncthreads();
    if (ro == 0) {
        for (int i = 1; i < rpi; i++) {
            float4 o = redS[t + i * groups];
            s.x += o.x; s.y += o.y; s.z += o.z; s.w += o.w;
            float4 p = redQ[t + i * groups];
            q.x += p.x; q.y += p.y; q.z += p.z; q.w += p.w;
        }
        int k = blockIdx.x;
        psum[(size_t)(4 * g + 0) * chunks + k] = s.x;
        psum[(size_t)(4 * g + 1) * chunks + k] = s.y;
        psum[(size_t)(4 * g + 2) * chunks + k] = s.z;
        psum[(size_t)(4 * g + 3) * chunks + k] = s.w;
        psumsq[(size_t)(4 * g + 0) * chunks + k] = q.x;
        psumsq[(size_t)(4 * g + 1) * chunks + k] = q.y;
        psumsq[(size_t)(4 * g + 2) * chunks + k] = q.z;
        psumsq[(size_t)(4 * g + 3) * chunks + k] = q.w;
    }
}

// one wave per channel; coalesced lane-parallel reduce -> scale/shift.
__global__ __launch_bounds__(256) void bn_reduce_kernel(
    const float* __restrict__ psum, const float* __restrict__ psumsq,
    const float* __restrict__ gamma, const float* __restrict__ beta,
    float* __restrict__ scale, float* __restrict__ shift,
    int N, int chunks) {
    int wave = threadIdx.x >> 6;
    int lane = threadIdx.x & 63;
    int c = blockIdx.x * 4 + wave;
    float s = 0.f, q = 0.f;
    for (int k = lane; k < chunks; k += 64) {
        s += psum[(size_t)c * chunks + k];
        q += psumsq[(size_t)c * chunks + k];
    }
#pragma unroll
    for (int off = 32; off > 0; off >>= 1) {
        s += __shfl_down(s, off, 64);
        q += __shfl_down(q, off, 64);
    }
    if (lane == 0) {
        float invN = 1.0f / (float)N;
        float mean = s * invN;
        float var = q * invN - mean * mean;
        float sc = gamma[c] * rsqrtf(var + BN_EPS);
        scale[c] = sc;
        shift[c] = beta[c] - mean * sc;
    }
}

// ---------------- final: out = relu(bn2(h2) + x), large grid (bf16 h2) ------

__global__ void final_kernel(const ushort* __restrict__ h2, const float* __restrict__ x,
                             const float* __restrict__ scale, const float* __restrict__ shift,
                             float* __restrict__ out, int total4, int C4) {
    int idx = blockIdx.x * blockDim.x + threadIdx.x;
    if (idx >= total4) return;
    int c4 = (idx & (C4 - 1)) * 4;
    ushort4 u = ((const ushort4*)h2)[idx];
    float4 xv = ((const float4*)x)[idx];
    float4 o;
    o.x = fmaxf(fmaf(bf2f(u.x), scale[c4 + 0], shift[c4 + 0]) + xv.x, 0.f);
    o.y = fmaxf(fmaf(bf2f(u.y), scale[c4 + 1], shift[c4 + 1]) + xv.y, 0.f);
    o.z = fmaxf(fmaf(bf2f(u.z), scale[c4 + 2], shift[c4 + 2]) + xv.z, 0.f);
    o.w = fmaxf(fmaf(bf2f(u.w), scale[c4 + 3], shift[c4 + 3]) + xv.w, 0.f);
    ((float4*)out)[idx] = o;
}

// ---------------- launch ----------------

extern "C" void kernel_launch(void* const* d_in, const int* in_sizes, int n_in,
                              void* d_out, int out_size, void* d_ws, size_t ws_size,
                              hipStream_t stream) {
    const float* x  = (const float*)d_in[0];
    const int*   es = (const int*)d_in[1];
    const float* W1 = (const float*)d_in[2];
    const float* g1 = (const float*)d_in[3];
    const float* b1 = (const float*)d_in[4];
    const float* W2 = (const float*)d_in[5];
    const float* g2 = (const float*)d_in[6];
    const float* b2 = (const float*)d_in[7];
    float* out = (float*)d_out;

    const int E  = in_sizes[1] / 2;
    const int IC = in_sizes[3];   // 512
    const int C  = in_sizes[7];   // 256
    const int N  = in_sizes[0] / C;
    const int MTILES = (N + 63) / 64;     // 157 (BM=64)
    const int CHUNKS2 = 512;

    const int* row = es;
    const int* col = es + E;

    // ---- workspace layout (cnt first: single memset) ----
    char* w = (char*)d_ws;
    size_t off = 0;
    auto alloc = [&](size_t bytes) -> void* {
        void* p = w + off;
        off = (off + bytes + 255) & ~(size_t)255;
        return p;
    };
    int*   cnt     = (int*)alloc((size_t)N * 4);
    float* dis     = (float*)alloc((size_t)N * 4);
    int*   rowptr  = (int*)alloc((size_t)(N + 1) * 4);
    int*   cursor  = (int*)alloc((size_t)N * 4);
    int2*  adjw    = (int2*)alloc((size_t)E * 8);
    float* psum1   = (float*)alloc((size_t)IC * MTILES * 4);
    float* psumsq1 = (float*)alloc((size_t)IC * MTILES * 4);
    float* psum2   = (float*)alloc((size_t)C * CHUNKS2 * 4);
    float* psumsq2 = (float*)alloc((size_t)C * CHUNKS2 * 4);
    float* scale1  = (float*)alloc((size_t)IC * 4);
    float* shift1  = (float*)alloc((size_t)IC * 4);
    float* scale2  = (float*)alloc((size_t)C * 4);
    float* shift2  = (float*)alloc((size_t)C * 4);
    ushort* xbf    = (ushort*)alloc((size_t)N * C * 2);
    ushort* W1bf   = (ushort*)alloc((size_t)IC * C * 2);
    ushort* W2bf   = (ushort*)alloc((size_t)IC * C * 2);
    ushort* g1x    = (ushort*)alloc((size_t)N * C * 2);
    ushort* h1raw  = (ushort*)alloc((size_t)N * IC * 2);  // GEMM1 out, bf16 (pre-BN)
    ushort* xl2bf  = (ushort*)alloc((size_t)N * C * 2);
    ushort* h2     = (ushort*)alloc((size_t)N * C * 2);   // gather2 out, bf16

    hipMemsetAsync(cnt, 0, (size_t)N * 4, stream);

    // ---- prep: degree count + bf16 casts ----
    {
        int n4x = N * C / 4, n4w = IC * C / 4;
        int tot = E + n4x + 2 * n4w;
        prep_kernel<<<(tot + 255) / 256, 256, 0, stream>>>(
            col, cnt, x, W1, W2, xbf, W1bf, W2bf, E, n4x, n4w);
    }
    scan_dis_kernel<<<1, 1024, 0, stream>>>(cnt, dis, rowptr, cursor, N);
    scatter_kernel<<<(E + 255) / 256, 256, 0, stream>>>(row, col, dis, cursor, adjw, E);

    // ---- layer 1: g1x = A_norm(x); h1raw = g1x @ W1^T (bf16 + stats1) ----
    gather_bf_kernel<<<(N + 3) / 4, 256, 0, stream>>>(xbf, rowptr, adjw, dis, g1x, N);
    {
        dim3 grid(IC / 128, MTILES);
        gemm_mfma_kernel<true, false><<<grid, 256, 0, stream>>>(
            g1x, W1bf, h1raw, psum1, psumsq1, nullptr, nullptr, MTILES, N, IC, C);
    }
    bn_reduce_kernel<<<IC / 4, 256, 0, stream>>>(psum1, psumsq1, g1, b1, scale1, shift1, N, MTILES);

    // ---- layer 2: xl2 = relu(bn1(h1raw)) @ W2^T (BN fused into A staging);
    //      h2 = A_norm(xl2) ----
    {
        dim3 grid(C / 128, MTILES);
        gemm_mfma_kernel<false, true><<<grid, 256, 0, stream>>>(
            h1raw, W2bf, xl2bf, scale1, shift1, scale1, shift1, 0, N, C, IC);
    }
    gather_bf_kernel<<<(N + 3) / 4, 256, 0, stream>>>(xl2bf, rowptr, adjw, dis, h2, N);
    {
        int rpc = (N + CHUNKS2 - 1) / CHUNKS2;
        bn_partial_kernel<<<CHUNKS2, 256, 0, stream>>>(h2, psum2, psumsq2, N, C, rpc, CHUNKS2);
    }
    bn_reduce_kernel<<<C / 4, 256, 0, stream>>>(psum2, psumsq2, g2, b2, scale2, shift2, N, CHUNKS2);

    // ---- epilogue: relu(bn2(h2) + x), saturating grid ----
    {
        int total4 = (N * C) / 4;
        final_kernel<<<(total4 + 255) / 256, 256, 0, stream>>>(h2, x, scale2, shift2, out, total4, C / 4);
    }
}